// Round 6
// baseline (3721.259 us; speedup 1.0000x reference)
//
#include <hip/hip_runtime.h>
#include <cstdint>
#include <cstddef>

// Problem constants (AugmentedLstm: B=64, T=512, D=512, H=512)
#define BB 64
#define TT 512
#define DD 512
#define HH 512
#define SIXH 3072
#define NWG 32           // persistent recurrence workgroups (j-slices of 16)

typedef __attribute__((ext_vector_type(8))) short bf16x8;
typedef __attribute__((ext_vector_type(4))) float f32x4;
typedef __attribute__((ext_vector_type(4))) unsigned short u16x4;
typedef __attribute__((ext_vector_type(4))) int i32x4;

// ---- ws layout (byte offsets) ---------------------------------------------
#define WS_FLAGS 0u        // 2 ints: [0] fp32-inputs flag, [1] int64-lengths flag
#define WS_CNT   256u      // 4 groups x 32 packed per-wave flags (512 B used)
#define WS_H     4352u     // 2 x [BB][HH] ushort bf16 h ping-pong (131072 B)
#define WS_C     135424u   // [BB][HH] float c (131072 B)
#define WS_PROJ  266496u   // proj chunk: [b][tl][6H] bf16, Tc*BB rows

// Coherent (L2-bypassing, L3-visible) 16B load / 8B store via explicit sc0 sc1.
#define CLOAD16(dst, ptr) \
    asm volatile("global_load_dwordx4 %0, %1, off sc0 sc1" : "=v"(dst) : "v"(ptr))
#define CSTORE8(ptr, val) \
    asm volatile("global_store_dwordx2 %0, %1, off sc0 sc1" :: "v"(ptr), "v"(val))
// waitcnt tied to the 4 regs of one ki-chunk so MFMAs can't be hoisted above it
#define WAIT4(N, a,b,c,d) \
    asm volatile("s_waitcnt vmcnt(" N ")" : "+v"(a),"+v"(b),"+v"(c),"+v"(d))

__device__ __forceinline__ float bf2f(unsigned short u) {
    union { unsigned int i; float f; } v; v.i = ((unsigned int)u) << 16; return v.f;
}
__device__ __forceinline__ unsigned short f2bf(float f) {
    union { unsigned int i; float f; } v; v.f = f;
    unsigned int r = v.i + 0x7FFFu + ((v.i >> 16) & 1u);  // RNE
    return (unsigned short)(r >> 16);
}
__device__ __forceinline__ float sigm(float x) { return 1.0f / (1.0f + __expf(-x)); }
__device__ __forceinline__ float tanh_fast(float x) {
    return 1.0f - 2.0f / (__expf(2.0f * x) + 1.0f);   // NaN-free, exact at +-inf
}

// vectorized f32->bf16x8: two float4 loads (32B-aligned at all call sites)
__device__ __forceinline__ bf16x8 cvt8v(const float* p) {
    const float4 a = *(const float4*)p;
    const float4 b = *(const float4*)(p + 4);
    bf16x8 o;
    o[0] = (short)f2bf(a.x); o[1] = (short)f2bf(a.y);
    o[2] = (short)f2bf(a.z); o[3] = (short)f2bf(a.w);
    o[4] = (short)f2bf(b.x); o[5] = (short)f2bf(b.y);
    o[6] = (short)f2bf(b.z); o[7] = (short)f2bf(b.w);
    return o;
}

// ---------------------------------------------------------------------------
// Detect input dtypes from raw bits (logic proven rounds 2-5).
// ---------------------------------------------------------------------------
__global__ void detect_kernel(const unsigned short* __restrict__ x16,
                              const int* __restrict__ len32,
                              int* __restrict__ flags) {
    const int lane = threadIdx.x;   // 64
    int bad = 0;
    for (int i = lane; i < 256; i += 64)
        if (fabsf(bf2f(x16[i])) > 1e4f) bad++;
#pragma unroll
    for (int off = 32; off; off >>= 1) bad += __shfl_down(bad, off);
    if (lane == 0) {
        flags[0] = (bad >= 16) ? 1 : 0;
        flags[1] = (len32[1] == 0 && len32[3] == 0 && len32[5] == 0) ? 1 : 0;
    }
}

// ---------------------------------------------------------------------------
// Proj chunk GEMM (proven core; FP32 path now uses float4 loads):
// projc[(b*Tc + tl)*6H + n] = x[b][t0+tl][:] . w_in[n][:] + b_in[n]
// ---------------------------------------------------------------------------
template<int FP32>
__device__ __forceinline__ void proj_core(const void* __restrict__ xv,
                                          const void* __restrict__ wv,
                                          const void* __restrict__ bv,
                                          unsigned short* __restrict__ projc,
                                          int t0, int tc_shift) {
    const int tid  = threadIdx.x;
    const int wave = tid >> 6;
    const int lane = tid & 63;
    const int q    = lane >> 4;
    const int r    = lane & 15;

    const int m_blk = blockIdx.y * 64 + (wave >> 1) * 32;
    const int n_blk = blockIdx.x * 64 + (wave & 1) * 32;
    const int Tc    = 1 << tc_shift;
    const int b     = m_blk >> tc_shift;
    const int tl    = m_blk & (Tc - 1);

    const size_t xrow0 = (size_t)(b * TT + t0 + tl + r) * DD;
    const size_t xrow1 = (size_t)(b * TT + t0 + tl + 16 + r) * DD;
    const size_t wrow0 = (size_t)(n_blk + r) * DD;
    const size_t wrow1 = (size_t)(n_blk + 16 + r) * DD;

    f32x4 acc[2][2] = {};
    const int koff = q * 8;
    for (int k0 = 0; k0 < DD; k0 += 32) {
        bf16x8 a0, a1, b0, b1;
        const int k = k0 + koff;
        if (FP32) {
            const float* xf = (const float*)xv;
            const float* wf = (const float*)wv;
            a0 = cvt8v(xf + xrow0 + k);  a1 = cvt8v(xf + xrow1 + k);
            b0 = cvt8v(wf + wrow0 + k);  b1 = cvt8v(wf + wrow1 + k);
        } else {
            const unsigned short* xb = (const unsigned short*)xv;
            const unsigned short* wb = (const unsigned short*)wv;
            a0 = *(const bf16x8*)(xb + xrow0 + k);  a1 = *(const bf16x8*)(xb + xrow1 + k);
            b0 = *(const bf16x8*)(wb + wrow0 + k);  b1 = *(const bf16x8*)(wb + wrow1 + k);
        }
        acc[0][0] = __builtin_amdgcn_mfma_f32_16x16x32_bf16(a0, b0, acc[0][0], 0, 0, 0);
        acc[0][1] = __builtin_amdgcn_mfma_f32_16x16x32_bf16(a0, b1, acc[0][1], 0, 0, 0);
        acc[1][0] = __builtin_amdgcn_mfma_f32_16x16x32_bf16(a1, b0, acc[1][0], 0, 0, 0);
        acc[1][1] = __builtin_amdgcn_mfma_f32_16x16x32_bf16(a1, b1, acc[1][1], 0, 0, 0);
    }

#pragma unroll
    for (int mi = 0; mi < 2; mi++) {
#pragma unroll
        for (int ni = 0; ni < 2; ni++) {
            const int n = n_blk + ni * 16 + r;
            const float bias = FP32 ? ((const float*)bv)[n] : bf2f(((const unsigned short*)bv)[n]);
#pragma unroll
            for (int rr = 0; rr < 4; rr++) {
                const int m = m_blk + mi * 16 + q * 4 + rr;
                projc[(size_t)m * SIXH + n] = f2bf(acc[mi][ni][rr] + bias);
            }
        }
    }
}

__global__ __launch_bounds__(256) void proj_kernel(const void* xv, const void* wv, const void* bv,
                                                   unsigned short* projc, const int* flags,
                                                   const int* __restrict__ len32,
                                                   int t0, int tc_shift) {
    // Dead-block skip: this y-block covers 64 rows of ONE batch b (Tc >= 64),
    // timesteps t0+tl0 .. t0+tl0+63. If even the first is past len[b], every
    // row feeds only zeroed outputs (rec kernel overrides t>=len), so skip.
    const int Tc  = 1 << tc_shift;
    const int mb  = blockIdx.y * 64;
    const int b   = mb >> tc_shift;
    const int tl0 = mb & (Tc - 1);
    const int len_b = flags[1] ? len32[2 * b] : len32[b];
    if (t0 + tl0 >= len_b) return;

    if (flags[0]) proj_core<1>(xv, wv, bv, projc, t0, tc_shift);
    else          proj_core<0>(xv, wv, bv, projc, t0, tc_shift);
}

// ---------------------------------------------------------------------------
// Persistent recurrence kernel v6. Grid: NWG=32 x 256 threads (4 waves).
// Wave w owns batches [w*16, w*16+16); block owns j in [wg*16, wg*16+16).
//
// vs v5 (measured 2825us, MfmaUtil 1.2%, all pipes idle => latency chain):
// the per-step chain included ~0.5-1.6us of LDS weight re-reads (each wave
// re-read its whole 80KB slice every step; 320 ds_read_b128/CU/step, every
// MFMA dependent on one). Weights are STEP-INVARIANT and occupancy is 1
// block/CU => ~512 VGPR/wave available, only 100 used. So: gates 0-3 (i,f,
// g,o) now live in per-lane VGPRs (256 regs, loaded once); gate 4 (hw)
// stays in LDS (16KB) to keep total VGPR ~400 < the 450 no-spill line.
// Sync structure (group-split handshake, Lmax skip) unchanged from v5.
// ---------------------------------------------------------------------------
__global__ __launch_bounds__(256, 1) void rec_kernel(
    const unsigned short* __restrict__ projc,
    const void* __restrict__ wsv, const void* __restrict__ bsv,
    const int* __restrict__ len32,
    unsigned short* __restrict__ hbuf, float* __restrict__ cbuf,
    int* __restrict__ wgflag, void* __restrict__ outv,
    const int* __restrict__ flags, int t0, int Tc)
{
    const int fp32 = flags[0], i64 = flags[1];
    const int tid  = threadIdx.x;
    const int wv   = tid >> 6;    // wave = batch group (0..3)
    const int lane = tid & 63;
    const int q    = lane >> 4;
    const int r    = lane & 15;
    const int j0   = blockIdx.x * 16;
    const int b    = wv * 16 + r;              // this lane's batch

    // hw-gate W_state slice only: [16 ki][64 lanes][8 ushort] = 16 KB
    __shared__ unsigned short wlds[16 * 64 * 8];

    for (int v = tid; v < 16 * 64; v += 256) {
        const int ki = v >> 6;
        const int ln = v & 63;
        const size_t gaddr = (size_t)(4 * HH + j0 + (ln & 15)) * HH + ki * 32 + (ln >> 4) * 8;
        bf16x8 w8;
        if (fp32) w8 = cvt8v((const float*)wsv + gaddr);
        else      w8 = *(const bf16x8*)((const unsigned short*)wsv + gaddr);
        *(bf16x8*)&wlds[(size_t)v * 8] = w8;
    }

    // gates 0-3: per-lane register-resident weight fragments (loaded once).
    // Same frag layout as the old LDS path with ln = lane.
    bf16x8 wreg[4][16];
#pragma unroll
    for (int g = 0; g < 4; g++)
#pragma unroll
        for (int ki = 0; ki < 16; ki++) {
            const size_t gaddr = (size_t)(g * HH + j0 + (lane & 15)) * HH + ki * 32 + (lane >> 4) * 8;
            if (fp32) wreg[g][ki] = cvt8v((const float*)wsv + gaddr);
            else      wreg[g][ki] = *(const bf16x8*)((const unsigned short*)wsv + gaddr);
        }

    // per-lane persistent state: lane owns batch b x (j = j0+q*4+jj)
    float bs[5][4];
#pragma unroll
    for (int g = 0; g < 5; g++)
#pragma unroll
        for (int jj = 0; jj < 4; jj++)
            bs[g][jj] = fp32 ? ((const float*)bsv)[g * HH + j0 + q * 4 + jj]
                             : bf2f(((const unsigned short*)bsv)[g * HH + j0 + q * 4 + jj]);

    const int len = i64 ? len32[2 * b] : len32[b];

    // Lmax = max over all batches (order-independent; uniform across waves)
    int Lmax = 0;
    for (int i = 0; i < BB; i++) {
        const int li = i64 ? len32[2 * i] : len32[i];
        Lmax = (li > Lmax) ? li : Lmax;
    }

    float creg[4];
#pragma unroll
    for (int jj = 0; jj < 4; jj++)
        creg[jj] = cbuf[b * HH + j0 + q * 4 + jj];

    // initial projc gate inputs for tl = 0 (overlaps the staging above)
    u16x4 pv[6];
    {
        const unsigned short* pb = projc + (size_t)b * Tc * SIXH + j0 + q * 4;
#pragma unroll
        for (int g = 0; g < 6; g++) pv[g] = *(const u16x4*)(pb + g * HH);
    }

    __syncthreads();   // wlds (hw gate) ready (only barrier in the kernel)

    union HU { i32x4 i; bf16x8 b; };
    union P8 { unsigned short s[4]; unsigned long long u; };

    int* const gflag = wgflag + wv * NWG;   // this batch-group's packed flag row

    for (int t = t0; t < t0 + Tc; t++) {
        // ---- dead tail: outputs are all-zero past Lmax; no sync, no GEMM ----
        if (t >= Lmax) {
            if (fp32) {
                float* op = (float*)outv + ((size_t)b * TT + t) * HH + j0 + q * 4;
                *(float4*)op = make_float4(0.f, 0.f, 0.f, 0.f);
            } else {
                unsigned short* op = (unsigned short*)outv + ((size_t)b * TT + t) * HH + j0 + q * 4;
                *(unsigned long long*)op = 0ull;
            }
            continue;
        }

        const unsigned short* hcur = hbuf + (size_t)(t & 1) * (BB * HH);
        unsigned short*       hnxt = hbuf + (size_t)((t + 1) & 1) * (BB * HH);

        if (t > t0) {   // wait until all 32 waves of THIS group published step t-1
            bool done;
            do {
                int f = (lane < NWG)
                    ? __hip_atomic_load(&gflag[lane], __ATOMIC_RELAXED,
                                        __HIP_MEMORY_SCOPE_AGENT)
                    : t;
                done = __all(f >= t);
            } while (!done);
            asm volatile("" ::: "memory");
        }

        // --- issue all 16 coherent h loads up-front (ki-major) ---
        i32x4 hv[16];
#pragma unroll
        for (int ki = 0; ki < 16; ki++)
            CLOAD16(hv[ki], hcur + (size_t)b * HH + ki * 32 + q * 8);

        // --- GEMM in 4 chunks, each gated by a register-tied partial wait.
        //     Gates 0-3 from VGPR (no memory dep); gate 4 from LDS. ---
        f32x4 acc[5] = {};
#define MFMA_CHUNK(KLO)                                                          \
        _Pragma("unroll")                                                        \
        for (int ki = (KLO); ki < (KLO) + 4; ki++) {                             \
            HU u; u.i = hv[ki];                                                  \
            _Pragma("unroll")                                                    \
            for (int g = 0; g < 4; g++)                                          \
                acc[g] = __builtin_amdgcn_mfma_f32_16x16x32_bf16(wreg[g][ki], u.b, acc[g], 0, 0, 0); \
            bf16x8 aw4 = *(const bf16x8*)&wlds[(ki * 64 + lane) * 8];            \
            acc[4] = __builtin_amdgcn_mfma_f32_16x16x32_bf16(aw4, u.b, acc[4], 0, 0, 0); \
        }
        WAIT4("12", hv[0],  hv[1],  hv[2],  hv[3]);   MFMA_CHUNK(0)
        WAIT4("8",  hv[4],  hv[5],  hv[6],  hv[7]);   MFMA_CHUNK(4)
        WAIT4("4",  hv[8],  hv[9],  hv[10], hv[11]);  MFMA_CHUNK(8)
        WAIT4("0",  hv[12], hv[13], hv[14], hv[15]);  MFMA_CHUNK(12)
#undef MFMA_CHUNK

        // --- epilogue: lane owns batch b x 4 consecutive j ---
        P8 hp;
        float ov4[4];
#pragma unroll
        for (int jj = 0; jj < 4; jj++) {
            const float i_g = sigm(bf2f(pv[0][jj]) + acc[0][jj] + bs[0][jj]);
            const float f_g = sigm(bf2f(pv[1][jj]) + acc[1][jj] + bs[1][jj]);
            const float g_t = tanh_fast(bf2f(pv[2][jj]) + acc[2][jj] + bs[2][jj]);
            const float o_g = sigm(bf2f(pv[3][jj]) + acc[3][jj] + bs[3][jj]);
            const float hw  = sigm(bf2f(pv[4][jj]) + acc[4][jj] + bs[4][jj]);

            float c_new = i_g * g_t + f_g * creg[jj];
            float ov = o_g * tanh_fast(c_new);
            ov = hw * ov + (1.0f - hw) * bf2f(pv[5][jj]);
            if (t >= len) { ov = 0.0f; c_new = 0.0f; }
            creg[jj] = c_new;
            ov4[jj] = ov;
            hp.s[jj] = f2bf(ov);
        }

        // h for next step: coherent 8B store; drain ONLY this wave's store,
        // then publish this wave's flag (per-wave, per-group handshake).
        CSTORE8((void*)(hnxt + (size_t)b * HH + j0 + q * 4), hp.u);
        asm volatile("s_waitcnt vmcnt(0)" ::: "memory");
        if (lane == 0)
            __hip_atomic_store(&gflag[blockIdx.x], t + 1,
                               __ATOMIC_RELAXED, __HIP_MEMORY_SCOPE_AGENT);

        // --- off-critical-path: output store + projc prefetch for t+1 ---
        if (fp32) {
            float* op = (float*)outv + ((size_t)b * TT + t) * HH + j0 + q * 4;
            *(float4*)op = make_float4(ov4[0], ov4[1], ov4[2], ov4[3]);
        } else {
            unsigned short* op = (unsigned short*)outv + ((size_t)b * TT + t) * HH + j0 + q * 4;
            *(unsigned long long*)op = hp.u;
        }
        const int tln = t - t0 + 1;
        if (tln < Tc) {
            const unsigned short* pb = projc + ((size_t)b * Tc + tln) * SIXH + j0 + q * 4;
#pragma unroll
            for (int g = 0; g < 6; g++) pv[g] = *(const u16x4*)(pb + g * HH);
        }
    }

    // persist c for chunked mode
#pragma unroll
    for (int jj = 0; jj < 4; jj++)
        cbuf[b * HH + j0 + q * 4 + jj] = creg[jj];
}

// ---------------------------------------------------------------------------
extern "C" void kernel_launch(void* const* d_in, const int* in_sizes, int n_in,
                              void* d_out, int out_size, void* d_ws, size_t ws_size,
                              hipStream_t stream) {
    const void* xv      = d_in[0];
    const int*  len     = (const int*)d_in[1];
    const void* w_in    = d_in[2];
    const void* b_in    = d_in[3];
    const void* w_state = d_in[4];
    const void* b_state = d_in[5];

    char* ws = (char*)d_ws;
    int* flags  = (int*)(ws + WS_FLAGS);
    int* wgflag = (int*)(ws + WS_CNT);
    unsigned short* hbuf = (unsigned short*)(ws + WS_H);
    float* cbuf = (float*)(ws + WS_C);
    unsigned short* projc = (unsigned short*)(ws + WS_PROJ);

    // Largest proj chunk (timesteps, power of 2, >= 64) fitting ws.
    int tc_shift = 9;
    while (tc_shift > 6 &&
           WS_PROJ + ((size_t)BB << tc_shift) * SIXH * 2 > ws_size) tc_shift--;
    const int Tc = 1 << tc_shift;

    detect_kernel<<<1, 64, 0, stream>>>((const unsigned short*)xv, len, flags);
    // zero wg flags + h ping-pong + c
    hipMemsetAsync(ws + WS_CNT, 0, WS_PROJ - WS_CNT, stream);

    for (int c = 0; c < TT / Tc; c++) {
        const int t0 = c * Tc;
        proj_kernel<<<dim3(SIXH / 64, (BB << tc_shift) >> 6), 256, 0, stream>>>(
            xv, w_in, b_in, projc, flags, len, t0, tc_shift);
        rec_kernel<<<NWG, 256, 0, stream>>>(projc, w_state, b_state, len,
                                            hbuf, cbuf, wgflag, d_out, flags, t0, Tc);
    }
}

// Round 7
// 3023.599 us; speedup vs baseline: 1.2307x; 1.2307x over previous
//
#include <hip/hip_runtime.h>
#include <cstdint>
#include <cstddef>

// Problem constants (AugmentedLstm: B=64, T=512, D=512, H=512)
#define BB 64
#define TT 512
#define DD 512
#define HH 512
#define SIXH 3072
#define NWG 32           // persistent recurrence workgroups (j-slices of 16)

typedef __attribute__((ext_vector_type(8))) short bf16x8;
typedef __attribute__((ext_vector_type(4))) float f32x4;
typedef __attribute__((ext_vector_type(4))) unsigned short u16x4;
typedef __attribute__((ext_vector_type(4))) int i32x4;

// ---- ws layout (byte offsets) ---------------------------------------------
// v7: flags spread one-per-128B-line: 4 groups x 32 WGs x 32 ints = 16 KB.
#define WS_FLAGS 0u        // 2 ints: [0] fp32-inputs flag, [1] int64-lengths flag
#define WS_CNT   256u      // 128 flag lines (4 groups x 32 WGs), stride 128 B
#define WS_H     16640u    // 2 x [BB][HH] ushort bf16 h ping-pong (131072 B)
#define WS_C     147712u   // [BB][HH] float c (131072 B)
#define WS_PROJ  278784u   // proj chunk: [b][tl][6H] bf16, Tc*BB rows

// Coherent (L2-bypassing, L3-visible) 16B load / 8B store via explicit sc0 sc1.
#define CLOAD16(dst, ptr) \
    asm volatile("global_load_dwordx4 %0, %1, off sc0 sc1" : "=v"(dst) : "v"(ptr))
#define CSTORE8(ptr, val) \
    asm volatile("global_store_dwordx2 %0, %1, off sc0 sc1" :: "v"(ptr), "v"(val))
// waitcnt tied to the 4 regs of one ki-chunk so MFMAs can't be hoisted above it
#define WAIT4(N, a,b,c,d) \
    asm volatile("s_waitcnt vmcnt(" N ")" : "+v"(a),"+v"(b),"+v"(c),"+v"(d))

__device__ __forceinline__ float bf2f(unsigned short u) {
    union { unsigned int i; float f; } v; v.i = ((unsigned int)u) << 16; return v.f;
}
__device__ __forceinline__ unsigned short f2bf(float f) {
    union { unsigned int i; float f; } v; v.f = f;
    unsigned int r = v.i + 0x7FFFu + ((v.i >> 16) & 1u);  // RNE
    return (unsigned short)(r >> 16);
}
__device__ __forceinline__ float sigm(float x) { return 1.0f / (1.0f + __expf(-x)); }
__device__ __forceinline__ float tanh_fast(float x) {
    return 1.0f - 2.0f / (__expf(2.0f * x) + 1.0f);   // NaN-free, exact at +-inf
}

// vectorized f32->bf16x8: two float4 loads (32B-aligned at all call sites)
__device__ __forceinline__ bf16x8 cvt8v(const float* p) {
    const float4 a = *(const float4*)p;
    const float4 b = *(const float4*)(p + 4);
    bf16x8 o;
    o[0] = (short)f2bf(a.x); o[1] = (short)f2bf(a.y);
    o[2] = (short)f2bf(a.z); o[3] = (short)f2bf(a.w);
    o[4] = (short)f2bf(b.x); o[5] = (short)f2bf(b.y);
    o[6] = (short)f2bf(b.z); o[7] = (short)f2bf(b.w);
    return o;
}

// ---------------------------------------------------------------------------
// Detect input dtypes from raw bits (logic proven rounds 2-5).
// ---------------------------------------------------------------------------
__global__ void detect_kernel(const unsigned short* __restrict__ x16,
                              const int* __restrict__ len32,
                              int* __restrict__ flags) {
    const int lane = threadIdx.x;   // 64
    int bad = 0;
    for (int i = lane; i < 256; i += 64)
        if (fabsf(bf2f(x16[i])) > 1e4f) bad++;
#pragma unroll
    for (int off = 32; off; off >>= 1) bad += __shfl_down(bad, off);
    if (lane == 0) {
        flags[0] = (bad >= 16) ? 1 : 0;
        flags[1] = (len32[1] == 0 && len32[3] == 0 && len32[5] == 0) ? 1 : 0;
    }
}

// ---------------------------------------------------------------------------
// Proj chunk GEMM (proven core; FP32 path uses float4 loads):
// projc[(b*Tc + tl)*6H + n] = x[b][t0+tl][:] . w_in[n][:] + b_in[n]
// ---------------------------------------------------------------------------
template<int FP32>
__device__ __forceinline__ void proj_core(const void* __restrict__ xv,
                                          const void* __restrict__ wv,
                                          const void* __restrict__ bv,
                                          unsigned short* __restrict__ projc,
                                          int t0, int tc_shift) {
    const int tid  = threadIdx.x;
    const int wave = tid >> 6;
    const int lane = tid & 63;
    const int q    = lane >> 4;
    const int r    = lane & 15;

    const int m_blk = blockIdx.y * 64 + (wave >> 1) * 32;
    const int n_blk = blockIdx.x * 64 + (wave & 1) * 32;
    const int Tc    = 1 << tc_shift;
    const int b     = m_blk >> tc_shift;
    const int tl    = m_blk & (Tc - 1);

    const size_t xrow0 = (size_t)(b * TT + t0 + tl + r) * DD;
    const size_t xrow1 = (size_t)(b * TT + t0 + tl + 16 + r) * DD;
    const size_t wrow0 = (size_t)(n_blk + r) * DD;
    const size_t wrow1 = (size_t)(n_blk + 16 + r) * DD;

    f32x4 acc[2][2] = {};
    const int koff = q * 8;
    for (int k0 = 0; k0 < DD; k0 += 32) {
        bf16x8 a0, a1, b0, b1;
        const int k = k0 + koff;
        if (FP32) {
            const float* xf = (const float*)xv;
            const float* wf = (const float*)wv;
            a0 = cvt8v(xf + xrow0 + k);  a1 = cvt8v(xf + xrow1 + k);
            b0 = cvt8v(wf + wrow0 + k);  b1 = cvt8v(wf + wrow1 + k);
        } else {
            const unsigned short* xb = (const unsigned short*)xv;
            const unsigned short* wb = (const unsigned short*)wv;
            a0 = *(const bf16x8*)(xb + xrow0 + k);  a1 = *(const bf16x8*)(xb + xrow1 + k);
            b0 = *(const bf16x8*)(wb + wrow0 + k);  b1 = *(const bf16x8*)(wb + wrow1 + k);
        }
        acc[0][0] = __builtin_amdgcn_mfma_f32_16x16x32_bf16(a0, b0, acc[0][0], 0, 0, 0);
        acc[0][1] = __builtin_amdgcn_mfma_f32_16x16x32_bf16(a0, b1, acc[0][1], 0, 0, 0);
        acc[1][0] = __builtin_amdgcn_mfma_f32_16x16x32_bf16(a1, b0, acc[1][0], 0, 0, 0);
        acc[1][1] = __builtin_amdgcn_mfma_f32_16x16x32_bf16(a1, b1, acc[1][1], 0, 0, 0);
    }

#pragma unroll
    for (int mi = 0; mi < 2; mi++) {
#pragma unroll
        for (int ni = 0; ni < 2; ni++) {
            const int n = n_blk + ni * 16 + r;
            const float bias = FP32 ? ((const float*)bv)[n] : bf2f(((const unsigned short*)bv)[n]);
#pragma unroll
            for (int rr = 0; rr < 4; rr++) {
                const int m = m_blk + mi * 16 + q * 4 + rr;
                projc[(size_t)m * SIXH + n] = f2bf(acc[mi][ni][rr] + bias);
            }
        }
    }
}

__global__ __launch_bounds__(256) void proj_kernel(const void* xv, const void* wv, const void* bv,
                                                   unsigned short* projc, const int* flags,
                                                   const int* __restrict__ len32,
                                                   int t0, int tc_shift) {
    // Dead-block skip (proven): rows past len[b] feed only zeroed outputs.
    const int Tc  = 1 << tc_shift;
    const int mb  = blockIdx.y * 64;
    const int b   = mb >> tc_shift;
    const int tl0 = mb & (Tc - 1);
    const int len_b = flags[1] ? len32[2 * b] : len32[b];
    if (t0 + tl0 >= len_b) return;

    if (flags[0]) proj_core<1>(xv, wv, bv, projc, t0, tc_shift);
    else          proj_core<0>(xv, wv, bv, projc, t0, tc_shift);
}

// ---------------------------------------------------------------------------
// Persistent recurrence kernel v7. Grid: NWG=32 x 256 threads (4 waves).
// Wave w owns batches [w*16, w*16+16); block owns j in [wg*16, wg*16+16).
//
// vs v6 (2941us; weights-in-VGPR was NEGATIVE -> reverted to v5 LDS core):
// v5/v6 packed each group's 32 flags into ONE 128B line -> per step, 32
// stores from 32 different CUs/XCDs serialize on that L3 line (~1.5-2.5us)
// while 32 pollers hammer it. v7 spreads flags ONE PER 128B LINE
// (4 groups x 32 WGs x 128B = 16KB): publisher has a private line (no
// store-store contention); poller gathers the 32 lines with 32 independent
// lane-parallel loads (one latency, MLP). Handshake semantics unchanged.
// ---------------------------------------------------------------------------
__global__ __launch_bounds__(256, 1) void rec_kernel(
    const unsigned short* __restrict__ projc,
    const void* __restrict__ wsv, const void* __restrict__ bsv,
    const int* __restrict__ len32,
    unsigned short* __restrict__ hbuf, float* __restrict__ cbuf,
    int* __restrict__ wgflag, void* __restrict__ outv,
    const int* __restrict__ flags, int t0, int Tc)
{
    const int fp32 = flags[0], i64 = flags[1];
    const int tid  = threadIdx.x;
    const int wv   = tid >> 6;    // wave = batch group (0..3)
    const int lane = tid & 63;
    const int q    = lane >> 4;
    const int r    = lane & 15;
    const int j0   = blockIdx.x * 16;
    const int b    = wv * 16 + r;              // this lane's batch

    // frag-linear W_state slice: [5 gates][16 ki][64 lanes][8 ushort] = 80 KB
    __shared__ unsigned short wlds[5 * 16 * 64 * 8];

    for (int v = tid; v < 5 * 16 * 64; v += 256) {
        const int g  = v >> 10;
        const int ki = (v >> 6) & 15;
        const int ln = v & 63;
        const size_t gaddr = (size_t)(g * HH + j0 + (ln & 15)) * HH + ki * 32 + (ln >> 4) * 8;
        bf16x8 w8;
        if (fp32) w8 = cvt8v((const float*)wsv + gaddr);
        else      w8 = *(const bf16x8*)((const unsigned short*)wsv + gaddr);
        *(bf16x8*)&wlds[(size_t)v * 8] = w8;
    }

    // per-lane persistent state: lane owns batch b x (j = j0+q*4+jj)
    float bs[5][4];
#pragma unroll
    for (int g = 0; g < 5; g++)
#pragma unroll
        for (int jj = 0; jj < 4; jj++)
            bs[g][jj] = fp32 ? ((const float*)bsv)[g * HH + j0 + q * 4 + jj]
                             : bf2f(((const unsigned short*)bsv)[g * HH + j0 + q * 4 + jj]);

    const int len = i64 ? len32[2 * b] : len32[b];

    // Lmax = max over all batches (order-independent; uniform across waves)
    int Lmax = 0;
    for (int i = 0; i < BB; i++) {
        const int li = i64 ? len32[2 * i] : len32[i];
        Lmax = (li > Lmax) ? li : Lmax;
    }

    float creg[4];
#pragma unroll
    for (int jj = 0; jj < 4; jj++)
        creg[jj] = cbuf[b * HH + j0 + q * 4 + jj];

    // initial projc gate inputs for tl = 0 (overlaps the wlds staging above)
    u16x4 pv[6];
    {
        const unsigned short* pb = projc + (size_t)b * Tc * SIXH + j0 + q * 4;
#pragma unroll
        for (int g = 0; g < 6; g++) pv[g] = *(const u16x4*)(pb + g * HH);
    }

    __syncthreads();   // wlds ready (only barrier in the kernel)

    union HU { i32x4 i; bf16x8 b; };
    union P8 { unsigned short s[4]; unsigned long long u; };

    // group wv's flag block: 32 lines of 128B (32 ints stride per WG)
    int* const gbase = wgflag + (size_t)wv * NWG * 32;

    for (int t = t0; t < t0 + Tc; t++) {
        // ---- dead tail: outputs are all-zero past Lmax; no sync, no GEMM ----
        if (t >= Lmax) {
            if (fp32) {
                float* op = (float*)outv + ((size_t)b * TT + t) * HH + j0 + q * 4;
                *(float4*)op = make_float4(0.f, 0.f, 0.f, 0.f);
            } else {
                unsigned short* op = (unsigned short*)outv + ((size_t)b * TT + t) * HH + j0 + q * 4;
                *(unsigned long long*)op = 0ull;
            }
            continue;
        }

        const unsigned short* hcur = hbuf + (size_t)(t & 1) * (BB * HH);
        unsigned short*       hnxt = hbuf + (size_t)((t + 1) & 1) * (BB * HH);

        if (t > t0) {   // wait until all 32 waves of THIS group published step t-1
            bool done;
            do {
                int f = (lane < NWG)
                    ? __hip_atomic_load(&gbase[lane * 32], __ATOMIC_RELAXED,
                                        __HIP_MEMORY_SCOPE_AGENT)
                    : t;
                done = __all(f >= t);
            } while (!done);
            asm volatile("" ::: "memory");
        }

        // --- issue all 16 coherent h loads up-front (ki-major) ---
        i32x4 hv[16];
#pragma unroll
        for (int ki = 0; ki < 16; ki++)
            CLOAD16(hv[ki], hcur + (size_t)b * HH + ki * 32 + q * 8);

        // --- GEMM in 4 chunks, each gated by a register-tied partial wait ---
        f32x4 acc[5] = {};
#define MFMA_CHUNK(KLO)                                                          \
        _Pragma("unroll")                                                        \
        for (int ki = (KLO); ki < (KLO) + 4; ki++) {                             \
            HU u; u.i = hv[ki];                                                  \
            _Pragma("unroll")                                                    \
            for (int g = 0; g < 5; g++) {                                        \
                bf16x8 aw = *(const bf16x8*)&wlds[((g * 16 + ki) * 64 + lane) * 8]; \
                acc[g] = __builtin_amdgcn_mfma_f32_16x16x32_bf16(aw, u.b, acc[g], 0, 0, 0); \
            }                                                                    \
        }
        WAIT4("12", hv[0],  hv[1],  hv[2],  hv[3]);   MFMA_CHUNK(0)
        WAIT4("8",  hv[4],  hv[5],  hv[6],  hv[7]);   MFMA_CHUNK(4)
        WAIT4("4",  hv[8],  hv[9],  hv[10], hv[11]);  MFMA_CHUNK(8)
        WAIT4("0",  hv[12], hv[13], hv[14], hv[15]);  MFMA_CHUNK(12)
#undef MFMA_CHUNK

        // --- epilogue: lane owns batch b x 4 consecutive j ---
        P8 hp;
        float ov4[4];
#pragma unroll
        for (int jj = 0; jj < 4; jj++) {
            const float i_g = sigm(bf2f(pv[0][jj]) + acc[0][jj] + bs[0][jj]);
            const float f_g = sigm(bf2f(pv[1][jj]) + acc[1][jj] + bs[1][jj]);
            const float g_t = tanh_fast(bf2f(pv[2][jj]) + acc[2][jj] + bs[2][jj]);
            const float o_g = sigm(bf2f(pv[3][jj]) + acc[3][jj] + bs[3][jj]);
            const float hw  = sigm(bf2f(pv[4][jj]) + acc[4][jj] + bs[4][jj]);

            float c_new = i_g * g_t + f_g * creg[jj];
            float ov = o_g * tanh_fast(c_new);
            ov = hw * ov + (1.0f - hw) * bf2f(pv[5][jj]);
            if (t >= len) { ov = 0.0f; c_new = 0.0f; }
            creg[jj] = c_new;
            ov4[jj] = ov;
            hp.s[jj] = f2bf(ov);
        }

        // h for next step: coherent 8B store; drain ONLY this wave's store,
        // then publish this wave's flag (private 128B line, no contention).
        CSTORE8((void*)(hnxt + (size_t)b * HH + j0 + q * 4), hp.u);
        asm volatile("s_waitcnt vmcnt(0)" ::: "memory");
        if (lane == 0)
            __hip_atomic_store(&gbase[blockIdx.x * 32], t + 1,
                               __ATOMIC_RELAXED, __HIP_MEMORY_SCOPE_AGENT);

        // --- off-critical-path: output store + projc prefetch for t+1 ---
        if (fp32) {
            float* op = (float*)outv + ((size_t)b * TT + t) * HH + j0 + q * 4;
            *(float4*)op = make_float4(ov4[0], ov4[1], ov4[2], ov4[3]);
        } else {
            unsigned short* op = (unsigned short*)outv + ((size_t)b * TT + t) * HH + j0 + q * 4;
            *(unsigned long long*)op = hp.u;
        }
        const int tln = t - t0 + 1;
        if (tln < Tc) {
            const unsigned short* pb = projc + ((size_t)b * Tc + tln) * SIXH + j0 + q * 4;
#pragma unroll
            for (int g = 0; g < 6; g++) pv[g] = *(const u16x4*)(pb + g * HH);
        }
    }

    // persist c for chunked mode
#pragma unroll
    for (int jj = 0; jj < 4; jj++)
        cbuf[b * HH + j0 + q * 4 + jj] = creg[jj];
}

// ---------------------------------------------------------------------------
extern "C" void kernel_launch(void* const* d_in, const int* in_sizes, int n_in,
                              void* d_out, int out_size, void* d_ws, size_t ws_size,
                              hipStream_t stream) {
    const void* xv      = d_in[0];
    const int*  len     = (const int*)d_in[1];
    const void* w_in    = d_in[2];
    const void* b_in    = d_in[3];
    const void* w_state = d_in[4];
    const void* b_state = d_in[5];

    char* ws = (char*)d_ws;
    int* flags  = (int*)(ws + WS_FLAGS);
    int* wgflag = (int*)(ws + WS_CNT);
    unsigned short* hbuf = (unsigned short*)(ws + WS_H);
    float* cbuf = (float*)(ws + WS_C);
    unsigned short* projc = (unsigned short*)(ws + WS_PROJ);

    // Largest proj chunk (timesteps, power of 2, >= 64) fitting ws.
    int tc_shift = 9;
    while (tc_shift > 6 &&
           WS_PROJ + ((size_t)BB << tc_shift) * SIXH * 2 > ws_size) tc_shift--;
    const int Tc = 1 << tc_shift;

    detect_kernel<<<1, 64, 0, stream>>>((const unsigned short*)xv, len, flags);
    // zero flag lines + h ping-pong + c
    hipMemsetAsync(ws + WS_CNT, 0, WS_PROJ - WS_CNT, stream);

    for (int c = 0; c < TT / Tc; c++) {
        const int t0 = c * Tc;
        proj_kernel<<<dim3(SIXH / 64, (BB << tc_shift) >> 6), 256, 0, stream>>>(
            xv, w_in, b_in, projc, flags, len, t0, tc_shift);
        rec_kernel<<<NWG, 256, 0, stream>>>(projc, w_state, b_state, len,
                                            hbuf, cbuf, wgflag, d_out, flags, t0, Tc);
    }
}

// Round 9
// 2704.128 us; speedup vs baseline: 1.3761x; 1.1181x over previous
//
#include <hip/hip_runtime.h>
#include <cstdint>
#include <cstddef>

// Problem constants (AugmentedLstm: B=64, T=512, D=512, H=512)
#define BB 64
#define TT 512
#define DD 512
#define HH 512
#define SIXH 3072
#define NWG 32           // persistent recurrence workgroups (j-slices of 16)

typedef __attribute__((ext_vector_type(8))) short bf16x8;
typedef __attribute__((ext_vector_type(4))) float f32x4;
typedef __attribute__((ext_vector_type(4))) unsigned short u16x4;
typedef __attribute__((ext_vector_type(4))) int i32x4;

// ---- ws layout (byte offsets) ---------------------------------------------
#define WS_FLAGS 0u          // 2 ints: [0] fp32-inputs flag, [1] int64-lengths flag
#define WS_CNT   256u        // 128 flag lines (4 groups x 32 WGs), stride 128 B
#define WS_H     16640u      // 2 x [BB][HH] ushort bf16 h ping-pong (131072 B)
#define WS_C     147712u     // [BB][HH] float c (131072 B)
#define WS_XB    278784u     // x as bf16 [BB][TT][DD] (33554432 B)
#define WS_WB    33833216u   // w_in as bf16 [6H][DD] (3145728 B)
#define WS_BF    36978944u   // b_in as f32 [6H] (12288 B)
#define WS_PROJ  36991232u   // proj chunk: [b][tl][6H] bf16, Tc*BB rows

// Coherent (L2-bypassing, L3-visible) 16B load / 8B store via explicit sc0 sc1.
#define CLOAD16(dst, ptr) \
    asm volatile("global_load_dwordx4 %0, %1, off sc0 sc1" : "=v"(dst) : "v"(ptr))
#define CSTORE8(ptr, val) \
    asm volatile("global_store_dwordx2 %0, %1, off sc0 sc1" :: "v"(ptr), "v"(val))
// waitcnt tied to the 4 regs of one ki-chunk so MFMAs can't be hoisted above it
#define WAIT4(N, a,b,c,d) \
    asm volatile("s_waitcnt vmcnt(" N ")" : "+v"(a),"+v"(b),"+v"(c),"+v"(d))

__device__ __forceinline__ float bf2f(unsigned short u) {
    union { unsigned int i; float f; } v; v.i = ((unsigned int)u) << 16; return v.f;
}
__device__ __forceinline__ unsigned short f2bf(float f) {
    union { unsigned int i; float f; } v; v.f = f;
    unsigned int r = v.i + 0x7FFFu + ((v.i >> 16) & 1u);  // RNE
    return (unsigned short)(r >> 16);
}
__device__ __forceinline__ float sigm(float x) { return 1.0f / (1.0f + __expf(-x)); }
__device__ __forceinline__ float tanh_fast(float x) {
    return 1.0f - 2.0f / (__expf(2.0f * x) + 1.0f);   // NaN-free, exact at +-inf
}

// vectorized f32->bf16x8: two float4 loads (32B-aligned at all call sites)
__device__ __forceinline__ bf16x8 cvt8v(const float* p) {
    const float4 a = *(const float4*)p;
    const float4 b = *(const float4*)(p + 4);
    bf16x8 o;
    o[0] = (short)f2bf(a.x); o[1] = (short)f2bf(a.y);
    o[2] = (short)f2bf(a.z); o[3] = (short)f2bf(a.w);
    o[4] = (short)f2bf(b.x); o[5] = (short)f2bf(b.y);
    o[6] = (short)f2bf(b.z); o[7] = (short)f2bf(b.w);
    return o;
}

// ---------------------------------------------------------------------------
// Detect input dtypes from raw bits (logic proven rounds 2-5).
// ---------------------------------------------------------------------------
__global__ void detect_kernel(const unsigned short* __restrict__ x16,
                              const int* __restrict__ len32,
                              int* __restrict__ flags) {
    const int lane = threadIdx.x;   // 64
    int bad = 0;
    for (int i = lane; i < 256; i += 64)
        if (fabsf(bf2f(x16[i])) > 1e4f) bad++;
#pragma unroll
    for (int off = 32; off; off >>= 1) bad += __shfl_down(bad, off);
    if (lane == 0) {
        flags[0] = (bad >= 16) ? 1 : 0;
        flags[1] = (len32[1] == 0 && len32[3] == 0 && len32[5] == 0) ? 1 : 0;
    }
}

// ---------------------------------------------------------------------------
// One-shot input conversion: x,w_in -> bf16 in ws; b_in -> f32 in ws.
// Removes the VALU-bound fp32->bf16 cvt from proj's inner loop (m80 lesson)
// and halves proj's global read bytes. Numerics identical: each element is
// RNE-rounded to bf16 exactly once (same as the old in-loop cvt8v); bias
// stays fp32 (added in fp32, rounded once at the end, as before).
// ---------------------------------------------------------------------------
__global__ __launch_bounds__(256) void convert_kernel(
    const void* __restrict__ xv, const void* __restrict__ wv,
    const void* __restrict__ bv,
    unsigned short* __restrict__ xb, unsigned short* __restrict__ wb,
    float* __restrict__ bf, const int* __restrict__ flags)
{
    const int fp32 = flags[0];
    const size_t NX = (size_t)BB * TT * DD;   // 16,777,216
    const size_t NW = (size_t)SIXH * DD;      //  1,572,864
    const size_t tid = (size_t)blockIdx.x * blockDim.x + threadIdx.x;
    const size_t stride = (size_t)gridDim.x * blockDim.x;

    if (fp32) {
        const float* xf = (const float*)xv;
        for (size_t i = tid * 4; i < NX; i += stride * 4) {
            const float4 v = *(const float4*)(xf + i);
            u16x4 o; o[0] = f2bf(v.x); o[1] = f2bf(v.y); o[2] = f2bf(v.z); o[3] = f2bf(v.w);
            *(u16x4*)(xb + i) = o;
        }
        const float* wf = (const float*)wv;
        for (size_t i = tid * 4; i < NW; i += stride * 4) {
            const float4 v = *(const float4*)(wf + i);
            u16x4 o; o[0] = f2bf(v.x); o[1] = f2bf(v.y); o[2] = f2bf(v.z); o[3] = f2bf(v.w);
            *(u16x4*)(wb + i) = o;
        }
        const float* bvf = (const float*)bv;
        for (size_t i = tid; i < SIXH; i += stride) bf[i] = bvf[i];
    } else {
        const unsigned short* xs = (const unsigned short*)xv;
        for (size_t i = tid * 4; i < NX; i += stride * 4)
            *(u16x4*)(xb + i) = *(const u16x4*)(xs + i);
        const unsigned short* wsrc = (const unsigned short*)wv;
        for (size_t i = tid * 4; i < NW; i += stride * 4)
            *(u16x4*)(wb + i) = *(const u16x4*)(wsrc + i);
        const unsigned short* bs = (const unsigned short*)bv;
        for (size_t i = tid; i < SIXH; i += stride) bf[i] = bf2f(bs[i]);
    }
}

// ---------------------------------------------------------------------------
// Proj chunk GEMM (proven core; now pure-bf16 inner loop, bias fp32):
// projc[(b*Tc + tl)*6H + n] = x[b][t0+tl][:] . w_in[n][:] + b_in[n]
// ---------------------------------------------------------------------------
__global__ __launch_bounds__(256) void proj_kernel(
    const unsigned short* __restrict__ xb, const unsigned short* __restrict__ wb,
    const float* __restrict__ bf, unsigned short* __restrict__ projc,
    const int* __restrict__ flags, const int* __restrict__ len32,
    int t0, int tc_shift)
{
    // Dead-block skip (proven): rows past len[b] feed only zeroed outputs.
    const int Tc  = 1 << tc_shift;
    {
        const int mb  = blockIdx.y * 64;
        const int bq  = mb >> tc_shift;
        const int tl0 = mb & (Tc - 1);
        const int len_b = flags[1] ? len32[2 * bq] : len32[bq];
        if (t0 + tl0 >= len_b) return;
    }

    const int tid  = threadIdx.x;
    const int wave = tid >> 6;
    const int lane = tid & 63;
    const int q    = lane >> 4;
    const int r    = lane & 15;

    const int m_blk = blockIdx.y * 64 + (wave >> 1) * 32;
    const int n_blk = blockIdx.x * 64 + (wave & 1) * 32;
    const int b     = m_blk >> tc_shift;
    const int tl    = m_blk & (Tc - 1);

    const size_t xrow0 = (size_t)(b * TT + t0 + tl + r) * DD;
    const size_t xrow1 = (size_t)(b * TT + t0 + tl + 16 + r) * DD;
    const size_t wrow0 = (size_t)(n_blk + r) * DD;
    const size_t wrow1 = (size_t)(n_blk + 16 + r) * DD;

    f32x4 acc[2][2] = {};
    const int koff = q * 8;
    for (int k0 = 0; k0 < DD; k0 += 32) {
        const int k = k0 + koff;
        bf16x8 a0 = *(const bf16x8*)(xb + xrow0 + k);
        bf16x8 a1 = *(const bf16x8*)(xb + xrow1 + k);
        bf16x8 b0 = *(const bf16x8*)(wb + wrow0 + k);
        bf16x8 b1 = *(const bf16x8*)(wb + wrow1 + k);
        acc[0][0] = __builtin_amdgcn_mfma_f32_16x16x32_bf16(a0, b0, acc[0][0], 0, 0, 0);
        acc[0][1] = __builtin_amdgcn_mfma_f32_16x16x32_bf16(a0, b1, acc[0][1], 0, 0, 0);
        acc[1][0] = __builtin_amdgcn_mfma_f32_16x16x32_bf16(a1, b0, acc[1][0], 0, 0, 0);
        acc[1][1] = __builtin_amdgcn_mfma_f32_16x16x32_bf16(a1, b1, acc[1][1], 0, 0, 0);
    }

#pragma unroll
    for (int mi = 0; mi < 2; mi++) {
#pragma unroll
        for (int ni = 0; ni < 2; ni++) {
            const int n = n_blk + ni * 16 + r;
            const float bias = bf[n];
#pragma unroll
            for (int rr = 0; rr < 4; rr++) {
                const int m = m_blk + mi * 16 + q * 4 + rr;
                projc[(size_t)m * SIXH + n] = f2bf(acc[mi][ni][rr] + bias);
            }
        }
    }
}

// ---------------------------------------------------------------------------
// Persistent recurrence kernel v8. Grid: NWG=32 x 256 threads (4 waves).
// Wave w owns batches [w*16, w*16+16); block owns j in [wg*16, wg*16+16).
//
// vs v7 (2218us, FETCH 545MB): ~250MB of that fetch was POLL traffic —
// every poll iteration re-loaded all 32 flag lines (L2-bypassed), hammering
// L3/fabric during exactly the window the handshake needs it. Flags are
// MONOTONE, so v8 caches the last-seen value per lane (fcache) and only
// re-loads lanes still below t (exec-masked). Steady state: only laggard
// WGs get polled. Handshake semantics unchanged.
// ---------------------------------------------------------------------------
__global__ __launch_bounds__(256, 1) void rec_kernel(
    const unsigned short* __restrict__ projc,
    const void* __restrict__ wsv, const void* __restrict__ bsv,
    const int* __restrict__ len32,
    unsigned short* __restrict__ hbuf, float* __restrict__ cbuf,
    int* __restrict__ wgflag, void* __restrict__ outv,
    const int* __restrict__ flags, int t0, int Tc)
{
    const int fp32 = flags[0], i64 = flags[1];
    const int tid  = threadIdx.x;
    const int wv   = tid >> 6;    // wave = batch group (0..3)
    const int lane = tid & 63;
    const int q    = lane >> 4;
    const int r    = lane & 15;
    const int j0   = blockIdx.x * 16;
    const int b    = wv * 16 + r;              // this lane's batch

    // frag-linear W_state slice: [5 gates][16 ki][64 lanes][8 ushort] = 80 KB
    __shared__ unsigned short wlds[5 * 16 * 64 * 8];

    for (int v = tid; v < 5 * 16 * 64; v += 256) {
        const int g  = v >> 10;
        const int ki = (v >> 6) & 15;
        const int ln = v & 63;
        const size_t gaddr = (size_t)(g * HH + j0 + (ln & 15)) * HH + ki * 32 + (ln >> 4) * 8;
        bf16x8 w8;
        if (fp32) w8 = cvt8v((const float*)wsv + gaddr);
        else      w8 = *(const bf16x8*)((const unsigned short*)wsv + gaddr);
        *(bf16x8*)&wlds[(size_t)v * 8] = w8;
    }

    // per-lane persistent state: lane owns batch b x (j = j0+q*4+jj)
    float bs[5][4];
#pragma unroll
    for (int g = 0; g < 5; g++)
#pragma unroll
        for (int jj = 0; jj < 4; jj++)
            bs[g][jj] = fp32 ? ((const float*)bsv)[g * HH + j0 + q * 4 + jj]
                             : bf2f(((const unsigned short*)bsv)[g * HH + j0 + q * 4 + jj]);

    const int len = i64 ? len32[2 * b] : len32[b];

    // Lmax = max over all batches (order-independent; uniform across waves)
    int Lmax = 0;
    for (int i = 0; i < BB; i++) {
        const int li = i64 ? len32[2 * i] : len32[i];
        Lmax = (li > Lmax) ? li : Lmax;
    }

    float creg[4];
#pragma unroll
    for (int jj = 0; jj < 4; jj++)
        creg[jj] = cbuf[b * HH + j0 + q * 4 + jj];

    // initial projc gate inputs for tl = 0 (overlaps the wlds staging above)
    u16x4 pv[6];
    {
        const unsigned short* pb = projc + (size_t)b * Tc * SIXH + j0 + q * 4;
#pragma unroll
        for (int g = 0; g < 6; g++) pv[g] = *(const u16x4*)(pb + g * HH);
    }

    __syncthreads();   // wlds ready (only barrier in the kernel)

    union HU { i32x4 i; bf16x8 b; };
    union P8 { unsigned short s[4]; unsigned long long u; };

    // group wv's flag block: 32 lines of 128B (32 ints stride per WG)
    int* const gbase = wgflag + (size_t)wv * NWG * 32;
    // monotone flag cache: lane l tracks WG l's flag; idle lanes pinned high
    int fcache = (lane < NWG) ? 0 : 0x7fffffff;

    for (int t = t0; t < t0 + Tc; t++) {
        // ---- dead tail: outputs are all-zero past Lmax; no sync, no GEMM ----
        if (t >= Lmax) {
            if (fp32) {
                float* op = (float*)outv + ((size_t)b * TT + t) * HH + j0 + q * 4;
                *(float4*)op = make_float4(0.f, 0.f, 0.f, 0.f);
            } else {
                unsigned short* op = (unsigned short*)outv + ((size_t)b * TT + t) * HH + j0 + q * 4;
                *(unsigned long long*)op = 0ull;
            }
            continue;
        }

        const unsigned short* hcur = hbuf + (size_t)(t & 1) * (BB * HH);
        unsigned short*       hnxt = hbuf + (size_t)((t + 1) & 1) * (BB * HH);

        if (t > t0) {   // wait until all 32 waves of THIS group published step t-1
            bool done;
            do {
                if (fcache < t)   // exec-masked: only laggard lanes re-load
                    fcache = __hip_atomic_load(&gbase[lane * 32], __ATOMIC_RELAXED,
                                               __HIP_MEMORY_SCOPE_AGENT);
                done = __all(fcache >= t);
            } while (!done);
            asm volatile("" ::: "memory");
        }

        // --- issue all 16 coherent h loads up-front (ki-major) ---
        i32x4 hv[16];
#pragma unroll
        for (int ki = 0; ki < 16; ki++)
            CLOAD16(hv[ki], hcur + (size_t)b * HH + ki * 32 + q * 8);

        // --- GEMM in 4 chunks, each gated by a register-tied partial wait ---
        f32x4 acc[5] = {};
#define MFMA_CHUNK(KLO)                                                          \
        _Pragma("unroll")                                                        \
        for (int ki = (KLO); ki < (KLO) + 4; ki++) {                             \
            HU u; u.i = hv[ki];                                                  \
            _Pragma("unroll")                                                    \
            for (int g = 0; g < 5; g++) {                                        \
                bf16x8 aw = *(const bf16x8*)&wlds[((g * 16 + ki) * 64 + lane) * 8]; \
                acc[g] = __builtin_amdgcn_mfma_f32_16x16x32_bf16(aw, u.b, acc[g], 0, 0, 0); \
            }                                                                    \
        }
        WAIT4("12", hv[0],  hv[1],  hv[2],  hv[3]);   MFMA_CHUNK(0)
        WAIT4("8",  hv[4],  hv[5],  hv[6],  hv[7]);   MFMA_CHUNK(4)
        WAIT4("4",  hv[8],  hv[9],  hv[10], hv[11]);  MFMA_CHUNK(8)
        WAIT4("0",  hv[12], hv[13], hv[14], hv[15]);  MFMA_CHUNK(12)
#undef MFMA_CHUNK

        // --- epilogue: lane owns batch b x 4 consecutive j ---
        P8 hp;
        float ov4[4];
#pragma unroll
        for (int jj = 0; jj < 4; jj++) {
            const float i_g = sigm(bf2f(pv[0][jj]) + acc[0][jj] + bs[0][jj]);
            const float f_g = sigm(bf2f(pv[1][jj]) + acc[1][jj] + bs[1][jj]);
            const float g_t = tanh_fast(bf2f(pv[2][jj]) + acc[2][jj] + bs[2][jj]);
            const float o_g = sigm(bf2f(pv[3][jj]) + acc[3][jj] + bs[3][jj]);
            const float hw  = sigm(bf2f(pv[4][jj]) + acc[4][jj] + bs[4][jj]);

            float c_new = i_g * g_t + f_g * creg[jj];
            float ov = o_g * tanh_fast(c_new);
            ov = hw * ov + (1.0f - hw) * bf2f(pv[5][jj]);
            if (t >= len) { ov = 0.0f; c_new = 0.0f; }
            creg[jj] = c_new;
            ov4[jj] = ov;
            hp.s[jj] = f2bf(ov);
        }

        // h for next step: coherent 8B store; drain ONLY this wave's store,
        // then publish this wave's flag (private 128B line, no contention).
        CSTORE8((void*)(hnxt + (size_t)b * HH + j0 + q * 4), hp.u);
        asm volatile("s_waitcnt vmcnt(0)" ::: "memory");
        if (lane == 0)
            __hip_atomic_store(&gbase[blockIdx.x * 32], t + 1,
                               __ATOMIC_RELAXED, __HIP_MEMORY_SCOPE_AGENT);

        // --- off-critical-path: output store + projc prefetch for t+1 ---
        if (fp32) {
            float* op = (float*)outv + ((size_t)b * TT + t) * HH + j0 + q * 4;
            *(float4*)op = make_float4(ov4[0], ov4[1], ov4[2], ov4[3]);
        } else {
            unsigned short* op = (unsigned short*)outv + ((size_t)b * TT + t) * HH + j0 + q * 4;
            *(unsigned long long*)op = hp.u;
        }
        const int tln = t - t0 + 1;
        if (tln < Tc) {
            const unsigned short* pb = projc + ((size_t)b * Tc + tln) * SIXH + j0 + q * 4;
#pragma unroll
            for (int g = 0; g < 6; g++) pv[g] = *(const u16x4*)(pb + g * HH);
        }
    }

    // persist c for chunked mode
#pragma unroll
    for (int jj = 0; jj < 4; jj++)
        cbuf[b * HH + j0 + q * 4 + jj] = creg[jj];
}

// ---------------------------------------------------------------------------
extern "C" void kernel_launch(void* const* d_in, const int* in_sizes, int n_in,
                              void* d_out, int out_size, void* d_ws, size_t ws_size,
                              hipStream_t stream) {
    const void* xv      = d_in[0];
    const int*  len     = (const int*)d_in[1];
    const void* w_in    = d_in[2];
    const void* b_in    = d_in[3];
    const void* w_state = d_in[4];
    const void* b_state = d_in[5];

    char* ws = (char*)d_ws;
    int* flags  = (int*)(ws + WS_FLAGS);
    int* wgflag = (int*)(ws + WS_CNT);
    unsigned short* hbuf = (unsigned short*)(ws + WS_H);
    float* cbuf = (float*)(ws + WS_C);
    unsigned short* xb = (unsigned short*)(ws + WS_XB);
    unsigned short* wb = (unsigned short*)(ws + WS_WB);
    float* bf = (float*)(ws + WS_BF);
    unsigned short* projc = (unsigned short*)(ws + WS_PROJ);

    // Largest proj chunk (timesteps, power of 2, >= 64) fitting ws.
    int tc_shift = 9;
    while (tc_shift > 6 &&
           WS_PROJ + ((size_t)BB << tc_shift) * SIXH * 2 > ws_size) tc_shift--;
    const int Tc = 1 << tc_shift;

    detect_kernel<<<1, 64, 0, stream>>>((const unsigned short*)xv, len, flags);
    // zero flag lines + h ping-pong + c (NOT the converted-input buffers)
    hipMemsetAsync(ws + WS_CNT, 0, WS_XB - WS_CNT, stream);
    convert_kernel<<<2048, 256, 0, stream>>>(xv, w_in, b_in, xb, wb, bf, flags);

    for (int c = 0; c < TT / Tc; c++) {
        const int t0 = c * Tc;
        proj_kernel<<<dim3(SIXH / 64, (BB << tc_shift) >> 6), 256, 0, stream>>>(
            xb, wb, bf, projc, flags, len, t0, tc_shift);
        rec_kernel<<<NWG, 256, 0, stream>>>(projc, w_state, b_state, len,
                                            hbuf, cbuf, wgflag, d_out, flags, t0, Tc);
    }
}

// Round 10
// 2552.077 us; speedup vs baseline: 1.4581x; 1.0596x over previous
//
#include <hip/hip_runtime.h>
#include <cstdint>
#include <cstddef>

// Problem constants (AugmentedLstm: B=64, T=512, D=512, H=512)
#define BB 64
#define TT 512
#define DD 512
#define HH 512
#define SIXH 3072
#define NWG 32           // persistent recurrence workgroups (j-slices of 16)

typedef __attribute__((ext_vector_type(8))) short bf16x8;
typedef __attribute__((ext_vector_type(4))) float f32x4;
typedef __attribute__((ext_vector_type(4))) unsigned short u16x4;
typedef __attribute__((ext_vector_type(4))) int i32x4;

// ---- ws layout (byte offsets) ---------------------------------------------
#define WS_FLAGS 0u          // 2 ints: [0] fp32-inputs flag, [1] int64-lengths flag
#define WS_CNT   256u        // 128 flag lines (4 groups x 32 WGs), stride 128 B
#define WS_H     16640u      // 2 x [BB][HH] ushort bf16 h ping-pong (131072 B)
#define WS_C     147712u     // [BB][HH] float c (131072 B)
#define WS_XB    278784u     // x as bf16 [BB][TT][DD] (33554432 B)
#define WS_WB    33833216u   // w_in as bf16 [6H][DD] (3145728 B)
#define WS_BF    36978944u   // b_in as f32 [6H] (12288 B)
#define WS_PROJ  36991232u   // proj chunk: [b][tl][6H] bf16, Tc*BB rows

// Coherent (L2-bypassing, L3-visible) 16B load / 8B store via explicit sc0 sc1.
#define CLOAD16(dst, ptr) \
    asm volatile("global_load_dwordx4 %0, %1, off sc0 sc1" : "=v"(dst) : "v"(ptr))
#define CSTORE8(ptr, val) \
    asm volatile("global_store_dwordx2 %0, %1, off sc0 sc1" :: "v"(ptr), "v"(val))
// waitcnt tied to the 4 regs of one ki-chunk so MFMAs can't be hoisted above it
#define WAIT4(N, a,b,c,d) \
    asm volatile("s_waitcnt vmcnt(" N ")" : "+v"(a),"+v"(b),"+v"(c),"+v"(d))

__device__ __forceinline__ float bf2f(unsigned short u) {
    union { unsigned int i; float f; } v; v.i = ((unsigned int)u) << 16; return v.f;
}
__device__ __forceinline__ unsigned short f2bf(float f) {
    union { unsigned int i; float f; } v; v.f = f;
    unsigned int r = v.i + 0x7FFFu + ((v.i >> 16) & 1u);  // RNE
    return (unsigned short)(r >> 16);
}
__device__ __forceinline__ float sigm(float x) { return 1.0f / (1.0f + __expf(-x)); }
__device__ __forceinline__ float tanh_fast(float x) {
    return 1.0f - 2.0f / (__expf(2.0f * x) + 1.0f);   // NaN-free, exact at +-inf
}

// vectorized f32->bf16x8: two float4 loads (32B-aligned at all call sites)
__device__ __forceinline__ bf16x8 cvt8v(const float* p) {
    const float4 a = *(const float4*)p;
    const float4 b = *(const float4*)(p + 4);
    bf16x8 o;
    o[0] = (short)f2bf(a.x); o[1] = (short)f2bf(a.y);
    o[2] = (short)f2bf(a.z); o[3] = (short)f2bf(a.w);
    o[4] = (short)f2bf(b.x); o[5] = (short)f2bf(b.y);
    o[6] = (short)f2bf(b.z); o[7] = (short)f2bf(b.w);
    return o;
}

// ---------------------------------------------------------------------------
// Detect input dtypes from raw bits (logic proven rounds 2-5).
// ---------------------------------------------------------------------------
__global__ void detect_kernel(const unsigned short* __restrict__ x16,
                              const int* __restrict__ len32,
                              int* __restrict__ flags) {
    const int lane = threadIdx.x;   // 64
    int bad = 0;
    for (int i = lane; i < 256; i += 64)
        if (fabsf(bf2f(x16[i])) > 1e4f) bad++;
#pragma unroll
    for (int off = 32; off; off >>= 1) bad += __shfl_down(bad, off);
    if (lane == 0) {
        flags[0] = (bad >= 16) ? 1 : 0;
        flags[1] = (len32[1] == 0 && len32[3] == 0 && len32[5] == 0) ? 1 : 0;
    }
}

// ---------------------------------------------------------------------------
// One-shot input conversion (proven r9): x,w_in -> bf16; b_in -> f32 in ws.
// ---------------------------------------------------------------------------
__global__ __launch_bounds__(256) void convert_kernel(
    const void* __restrict__ xv, const void* __restrict__ wv,
    const void* __restrict__ bv,
    unsigned short* __restrict__ xb, unsigned short* __restrict__ wb,
    float* __restrict__ bf, const int* __restrict__ flags)
{
    const int fp32 = flags[0];
    const size_t NX = (size_t)BB * TT * DD;   // 16,777,216
    const size_t NW = (size_t)SIXH * DD;      //  1,572,864
    const size_t tid = (size_t)blockIdx.x * blockDim.x + threadIdx.x;
    const size_t stride = (size_t)gridDim.x * blockDim.x;

    if (fp32) {
        const float* xf = (const float*)xv;
        for (size_t i = tid * 4; i < NX; i += stride * 4) {
            const float4 v = *(const float4*)(xf + i);
            u16x4 o; o[0] = f2bf(v.x); o[1] = f2bf(v.y); o[2] = f2bf(v.z); o[3] = f2bf(v.w);
            *(u16x4*)(xb + i) = o;
        }
        const float* wf = (const float*)wv;
        for (size_t i = tid * 4; i < NW; i += stride * 4) {
            const float4 v = *(const float4*)(wf + i);
            u16x4 o; o[0] = f2bf(v.x); o[1] = f2bf(v.y); o[2] = f2bf(v.z); o[3] = f2bf(v.w);
            *(u16x4*)(wb + i) = o;
        }
        const float* bvf = (const float*)bv;
        for (size_t i = tid; i < SIXH; i += stride) bf[i] = bvf[i];
    } else {
        const unsigned short* xs = (const unsigned short*)xv;
        for (size_t i = tid * 4; i < NX; i += stride * 4)
            *(u16x4*)(xb + i) = *(const u16x4*)(xs + i);
        const unsigned short* wsrc = (const unsigned short*)wv;
        for (size_t i = tid * 4; i < NW; i += stride * 4)
            *(u16x4*)(wb + i) = *(const u16x4*)(wsrc + i);
        const unsigned short* bs = (const unsigned short*)bv;
        for (size_t i = tid; i < SIXH; i += stride) bf[i] = bf2f(bs[i]);
    }
}

// ---------------------------------------------------------------------------
// Proj chunk GEMM v2: 64m x 192n per block, A-fragments held in registers
// and reused across 3 n-tiles (A global traffic /3). Core math per n-tile
// identical to the proven kernel.
// ---------------------------------------------------------------------------
__global__ __launch_bounds__(256) void proj_kernel(
    const unsigned short* __restrict__ xb, const unsigned short* __restrict__ wb,
    const float* __restrict__ bf, unsigned short* __restrict__ projc,
    const int* __restrict__ flags, const int* __restrict__ len32,
    int t0, int tc_shift)
{
    // Dead-block skip (proven): rows past len[b] feed only zeroed outputs.
    const int Tc  = 1 << tc_shift;
    {
        const int mb  = blockIdx.y * 64;
        const int bq  = mb >> tc_shift;
        const int tl0 = mb & (Tc - 1);
        const int len_b = flags[1] ? len32[2 * bq] : len32[bq];
        if (t0 + tl0 >= len_b) return;
    }

    const int tid  = threadIdx.x;
    const int wave = tid >> 6;
    const int lane = tid & 63;
    const int q    = lane >> 4;
    const int r    = lane & 15;

    const int m_blk  = blockIdx.y * 64 + (wave >> 1) * 32;
    const int n_base = blockIdx.x * 192 + (wave & 1) * 32;
    const int b      = m_blk >> tc_shift;
    const int tl     = m_blk & (Tc - 1);

    const size_t xrow0 = (size_t)(b * TT + t0 + tl + r) * DD;
    const size_t xrow1 = (size_t)(b * TT + t0 + tl + 16 + r) * DD;

    f32x4 acc[3][2][2] = {};
    const int koff = q * 8;
    for (int k0 = 0; k0 < DD; k0 += 32) {
        const int k = k0 + koff;
        const bf16x8 a0 = *(const bf16x8*)(xb + xrow0 + k);
        const bf16x8 a1 = *(const bf16x8*)(xb + xrow1 + k);
#pragma unroll
        for (int nt = 0; nt < 3; nt++) {
            const size_t wrow0 = (size_t)(n_base + nt * 64 + r) * DD;
            const size_t wrow1 = (size_t)(n_base + nt * 64 + 16 + r) * DD;
            bf16x8 b0 = *(const bf16x8*)(wb + wrow0 + k);
            bf16x8 b1 = *(const bf16x8*)(wb + wrow1 + k);
            acc[nt][0][0] = __builtin_amdgcn_mfma_f32_16x16x32_bf16(a0, b0, acc[nt][0][0], 0, 0, 0);
            acc[nt][0][1] = __builtin_amdgcn_mfma_f32_16x16x32_bf16(a0, b1, acc[nt][0][1], 0, 0, 0);
            acc[nt][1][0] = __builtin_amdgcn_mfma_f32_16x16x32_bf16(a1, b0, acc[nt][1][0], 0, 0, 0);
            acc[nt][1][1] = __builtin_amdgcn_mfma_f32_16x16x32_bf16(a1, b1, acc[nt][1][1], 0, 0, 0);
        }
    }

#pragma unroll
    for (int nt = 0; nt < 3; nt++)
#pragma unroll
        for (int mi = 0; mi < 2; mi++)
#pragma unroll
            for (int ni = 0; ni < 2; ni++) {
                const int n = n_base + nt * 64 + ni * 16 + r;
                const float bias = bf[n];
#pragma unroll
                for (int rr = 0; rr < 4; rr++) {
                    const int m = m_blk + mi * 16 + q * 4 + rr;
                    projc[(size_t)m * SIXH + n] = f2bf(acc[nt][mi][ni][rr] + bias);
                }
            }
}

// ---------------------------------------------------------------------------
// Persistent recurrence kernel v9. Grid: NWG=32 x 256 threads (4 waves).
// Wave w owns batches [w*16, w*16+16); block owns j in [wg*16, wg*16+16).
//
// vs v8 (2218us, FETCH unchanged -> poll-cache null result, poll traffic is
// NOT the bottleneck): two changes, both safe:
//  (a) PER-GROUP Lmax: groups are independent; lengths sorted descending so
//      group horizons are ~504/378/252/126 steps. Group w stops syncing at
//      its own Lmax_w -> total active-wave-steps drops to ~62%. This is also
//      the contention-vs-latency discriminator: if per-step cost is fabric/
//      CU contention, rec drops ~10-15%; if pure latency, flat.
//  (b) Two-phase detect: wait producers 0-15 -> issue h loads ki0-7 ->
//      wait 16-31 -> issue ki8-15. Overlaps half the h-load latency with
//      residual detection.
// ---------------------------------------------------------------------------
__global__ __launch_bounds__(256, 1) void rec_kernel(
    const unsigned short* __restrict__ projc,
    const void* __restrict__ wsv, const void* __restrict__ bsv,
    const int* __restrict__ len32,
    unsigned short* __restrict__ hbuf, float* __restrict__ cbuf,
    int* __restrict__ wgflag, void* __restrict__ outv,
    const int* __restrict__ flags, int t0, int Tc)
{
    const int fp32 = flags[0], i64 = flags[1];
    const int tid  = threadIdx.x;
    const int wv   = tid >> 6;    // wave = batch group (0..3)
    const int lane = tid & 63;
    const int q    = lane >> 4;
    const int r    = lane & 15;
    const int j0   = blockIdx.x * 16;
    const int b    = wv * 16 + r;              // this lane's batch

    // frag-linear W_state slice: [5 gates][16 ki][64 lanes][8 ushort] = 80 KB
    __shared__ unsigned short wlds[5 * 16 * 64 * 8];

    for (int v = tid; v < 5 * 16 * 64; v += 256) {
        const int g  = v >> 10;
        const int ki = (v >> 6) & 15;
        const int ln = v & 63;
        const size_t gaddr = (size_t)(g * HH + j0 + (ln & 15)) * HH + ki * 32 + (ln >> 4) * 8;
        bf16x8 w8;
        if (fp32) w8 = cvt8v((const float*)wsv + gaddr);
        else      w8 = *(const bf16x8*)((const unsigned short*)wsv + gaddr);
        *(bf16x8*)&wlds[(size_t)v * 8] = w8;
    }

    // per-lane persistent state: lane owns batch b x (j = j0+q*4+jj)
    float bs[5][4];
#pragma unroll
    for (int g = 0; g < 5; g++)
#pragma unroll
        for (int jj = 0; jj < 4; jj++)
            bs[g][jj] = fp32 ? ((const float*)bsv)[g * HH + j0 + q * 4 + jj]
                             : bf2f(((const unsigned short*)bsv)[g * HH + j0 + q * 4 + jj]);

    const int len = i64 ? len32[2 * b] : len32[b];

    // PER-GROUP Lmax: max over this wave's 16 batches (uniform within wave)
    int lmax_g = 0;
    for (int i = wv * 16; i < wv * 16 + 16; i++) {
        const int li = i64 ? len32[2 * i] : len32[i];
        lmax_g = (li > lmax_g) ? li : lmax_g;
    }

    float creg[4];
#pragma unroll
    for (int jj = 0; jj < 4; jj++)
        creg[jj] = cbuf[b * HH + j0 + q * 4 + jj];

    // initial projc gate inputs for tl = 0 (overlaps the wlds staging above)
    u16x4 pv[6];
    {
        const unsigned short* pb = projc + (size_t)b * Tc * SIXH + j0 + q * 4;
#pragma unroll
        for (int g = 0; g < 6; g++) pv[g] = *(const u16x4*)(pb + g * HH);
    }

    __syncthreads();   // wlds ready (only barrier in the kernel)

    union HU { i32x4 i; bf16x8 b; };
    union P8 { unsigned short s[4]; unsigned long long u; };

    // group wv's flag block: 32 lines of 128B (32 ints stride per WG)
    int* const gbase = wgflag + (size_t)wv * NWG * 32;
    // monotone flag cache: lane l tracks WG l's flag; idle lanes pinned high
    int fcache = (lane < NWG) ? 0 : 0x7fffffff;

    for (int t = t0; t < t0 + Tc; t++) {
        // ---- dead tail: this GROUP is done past lmax_g; no sync, no GEMM ----
        if (t >= lmax_g) {
            if (fp32) {
                float* op = (float*)outv + ((size_t)b * TT + t) * HH + j0 + q * 4;
                *(float4*)op = make_float4(0.f, 0.f, 0.f, 0.f);
            } else {
                unsigned short* op = (unsigned short*)outv + ((size_t)b * TT + t) * HH + j0 + q * 4;
                *(unsigned long long*)op = 0ull;
            }
            continue;
        }

        const unsigned short* hcur = hbuf + (size_t)(t & 1) * (BB * HH);
        unsigned short*       hnxt = hbuf + (size_t)((t + 1) & 1) * (BB * HH);

        // ---- phase 1: wait for producers 0..15, then issue h loads ki 0-7 ----
        if (t > t0) {
            while ((__ballot(fcache >= t) & 0xFFFFull) != 0xFFFFull) {
                if (fcache < t)
                    fcache = __hip_atomic_load(&gbase[lane * 32], __ATOMIC_RELAXED,
                                               __HIP_MEMORY_SCOPE_AGENT);
            }
            asm volatile("" ::: "memory");
        }
        i32x4 hv[16];
#pragma unroll
        for (int ki = 0; ki < 8; ki++)
            CLOAD16(hv[ki], hcur + (size_t)b * HH + ki * 32 + q * 8);

        // ---- phase 2: wait for producers 16..31, then issue ki 8-15 ----
        if (t > t0) {
            while (__ballot(fcache >= t) != ~0ull) {
                if (fcache < t)
                    fcache = __hip_atomic_load(&gbase[lane * 32], __ATOMIC_RELAXED,
                                               __HIP_MEMORY_SCOPE_AGENT);
            }
            asm volatile("" ::: "memory");
        }
#pragma unroll
        for (int ki = 8; ki < 16; ki++)
            CLOAD16(hv[ki], hcur + (size_t)b * HH + ki * 32 + q * 8);

        // --- GEMM in 4 chunks, each gated by a register-tied partial wait ---
        f32x4 acc[5] = {};
#define MFMA_CHUNK(KLO)                                                          \
        _Pragma("unroll")                                                        \
        for (int ki = (KLO); ki < (KLO) + 4; ki++) {                             \
            HU u; u.i = hv[ki];                                                  \
            _Pragma("unroll")                                                    \
            for (int g = 0; g < 5; g++) {                                        \
                bf16x8 aw = *(const bf16x8*)&wlds[((g * 16 + ki) * 64 + lane) * 8]; \
                acc[g] = __builtin_amdgcn_mfma_f32_16x16x32_bf16(aw, u.b, acc[g], 0, 0, 0); \
            }                                                                    \
        }
        WAIT4("12", hv[0],  hv[1],  hv[2],  hv[3]);   MFMA_CHUNK(0)
        WAIT4("8",  hv[4],  hv[5],  hv[6],  hv[7]);   MFMA_CHUNK(4)
        WAIT4("4",  hv[8],  hv[9],  hv[10], hv[11]);  MFMA_CHUNK(8)
        WAIT4("0",  hv[12], hv[13], hv[14], hv[15]);  MFMA_CHUNK(12)
#undef MFMA_CHUNK

        // --- epilogue: lane owns batch b x 4 consecutive j ---
        P8 hp;
        float ov4[4];
#pragma unroll
        for (int jj = 0; jj < 4; jj++) {
            const float i_g = sigm(bf2f(pv[0][jj]) + acc[0][jj] + bs[0][jj]);
            const float f_g = sigm(bf2f(pv[1][jj]) + acc[1][jj] + bs[1][jj]);
            const float g_t = tanh_fast(bf2f(pv[2][jj]) + acc[2][jj] + bs[2][jj]);
            const float o_g = sigm(bf2f(pv[3][jj]) + acc[3][jj] + bs[3][jj]);
            const float hw  = sigm(bf2f(pv[4][jj]) + acc[4][jj] + bs[4][jj]);

            float c_new = i_g * g_t + f_g * creg[jj];
            float ov = o_g * tanh_fast(c_new);
            ov = hw * ov + (1.0f - hw) * bf2f(pv[5][jj]);
            if (t >= len) { ov = 0.0f; c_new = 0.0f; }
            creg[jj] = c_new;
            ov4[jj] = ov;
            hp.s[jj] = f2bf(ov);
        }

        // h for next step: coherent 8B store; drain ONLY this wave's store,
        // then publish this wave's flag (private 128B line, no contention).
        CSTORE8((void*)(hnxt + (size_t)b * HH + j0 + q * 4), hp.u);
        asm volatile("s_waitcnt vmcnt(0)" ::: "memory");
        if (lane == 0)
            __hip_atomic_store(&gbase[blockIdx.x * 32], t + 1,
                               __ATOMIC_RELAXED, __HIP_MEMORY_SCOPE_AGENT);

        // --- off-critical-path: output store + projc prefetch for t+1 ---
        if (fp32) {
            float* op = (float*)outv + ((size_t)b * TT + t) * HH + j0 + q * 4;
            *(float4*)op = make_float4(ov4[0], ov4[1], ov4[2], ov4[3]);
        } else {
            unsigned short* op = (unsigned short*)outv + ((size_t)b * TT + t) * HH + j0 + q * 4;
            *(unsigned long long*)op = hp.u;
        }
        const int tln = t - t0 + 1;
        if (tln < Tc) {
            const unsigned short* pb = projc + ((size_t)b * Tc + tln) * SIXH + j0 + q * 4;
#pragma unroll
            for (int g = 0; g < 6; g++) pv[g] = *(const u16x4*)(pb + g * HH);
        }
    }

    // persist c for chunked mode
#pragma unroll
    for (int jj = 0; jj < 4; jj++)
        cbuf[b * HH + j0 + q * 4 + jj] = creg[jj];
}

// ---------------------------------------------------------------------------
extern "C" void kernel_launch(void* const* d_in, const int* in_sizes, int n_in,
                              void* d_out, int out_size, void* d_ws, size_t ws_size,
                              hipStream_t stream) {
    const void* xv      = d_in[0];
    const int*  len     = (const int*)d_in[1];
    const void* w_in    = d_in[2];
    const void* b_in    = d_in[3];
    const void* w_state = d_in[4];
    const void* b_state = d_in[5];

    char* ws = (char*)d_ws;
    int* flags  = (int*)(ws + WS_FLAGS);
    int* wgflag = (int*)(ws + WS_CNT);
    unsigned short* hbuf = (unsigned short*)(ws + WS_H);
    float* cbuf = (float*)(ws + WS_C);
    unsigned short* xb = (unsigned short*)(ws + WS_XB);
    unsigned short* wb = (unsigned short*)(ws + WS_WB);
    float* bf = (float*)(ws + WS_BF);
    unsigned short* projc = (unsigned short*)(ws + WS_PROJ);

    // Largest proj chunk (timesteps, power of 2, >= 64) fitting ws.
    int tc_shift = 9;
    while (tc_shift > 6 &&
           WS_PROJ + ((size_t)BB << tc_shift) * SIXH * 2 > ws_size) tc_shift--;
    const int Tc = 1 << tc_shift;

    detect_kernel<<<1, 64, 0, stream>>>((const unsigned short*)xv, len, flags);
    // zero flag lines + h ping-pong + c (NOT the converted-input buffers)
    hipMemsetAsync(ws + WS_CNT, 0, WS_XB - WS_CNT, stream);
    convert_kernel<<<2048, 256, 0, stream>>>(xv, w_in, b_in, xb, wb, bf, flags);

    for (int c = 0; c < TT / Tc; c++) {
        const int t0 = c * Tc;
        proj_kernel<<<dim3(SIXH / 192, (BB << tc_shift) >> 6), 256, 0, stream>>>(
            xb, wb, bf, projc, flags, len, t0, tc_shift);
        rec_kernel<<<NWG, 256, 0, stream>>>(projc, w_state, b_state, len,
                                            hbuf, cbuf, wgflag, d_out, flags, t0, Tc);
    }
}